// Round 12
// baseline (161.563 us; speedup 1.0000x reference)
//
#include <hip/hip_runtime.h>

// CTC loss forward (reduction='none', zero_infinity=True), matching the JAX ref.
// Shapes: log_probs (T,N,C)=(512,512,80) fp32, targets (N,S)=(512,128) i32.
// Output: (N,) fp32.
//
// R12 = R11 (fwd/bwd split, linear f32 mantissa + per-lane int exponent E,
// 3 trans/iter) + the stale-E fix from the R11 desk-check:
//  - BWD: lanes entirely above sA=2*tl are PERMANENTLY dead but kept E=0
//    (stale-high). The topmost live lane read Eup=0 while its own E decayed
//    -16 bits/step -> dE huge-positive -> fsc=2^(64-dE) flushed its OWN
//    mass to zero (~12 steps/lane, dead zone eating downward ~21 lanes over
//    the bwd half) -> dominant gamma_mid positions zeroed -> inf -> 0-loss.
//    FIX: init those lanes to E = -2^24: dE huge-NEGATIVE -> dc=dE, fsc=1
//    (own untouched), aln=0*0=0, Eb=E exactly; dead zone inert.
//  - dc cap 64 -> 110 (live-live dE bounded ~85 = 17 cross + 68 intra-lane
//    bits; mx < 2^113 no overflow; sc >= 2^-113 normal) so fsc==1 in every
//    live-live case.
// R11's fixes retained: NEGC readout guard (fmaxf handles 0/denorm/NaN),
// exact full-range alignment, dead test mx==0. Combine + R8 fallback proven.

#define NEGC  (-1.0e30f)
#define LOG2E 1.4426950408889634f
#define LN2   0.6931471805599453f

constexpr int T_ = 512;
constexpr int C_ = 80;
constexpr int S_ = 128;
constexpr int U_ = 8;        // register-ring depth / unroll
constexpr int WROW = 520;    // ws floats per n: ga @0 (257), gg @260 (257)
constexpr int BIGE = 1 << 24;
constexpr int DCAP = 110;    // dc cap: live-live dE <= ~85 < 110

__device__ __forceinline__ float exp2a(float x) { return __builtin_amdgcn_exp2f(x); }
__device__ __forceinline__ float log2a(float x) { return __builtin_amdgcn_logf(x); }

template <int CTRL>
__device__ __forceinline__ float dppf(float old_, float src) {
    return __int_as_float(__builtin_amdgcn_update_dpp(
        __float_as_int(old_), __float_as_int(src), CTRL, 0xF, 0xF, false));
}
template <int CTRL>
__device__ __forceinline__ int dppi(int old_, int src) {
    return __builtin_amdgcn_update_dpp(old_, src, CTRL, 0xF, 0xF, false);
}

// 2^k as f32: exact for k in [-126,127], EXACT 0 for k <= -127
// (callers guarantee k <= DCAP on the high side).
__device__ __forceinline__ float pow2f(int k) {
    int kc = k < -127 ? -127 : k;
    return __int_as_float((kc + 127) << 23);
}

// classic lse (combine/fallback only)
__device__ __forceinline__ float lse2(float x, float y) {
    float m = fmaxf(x, y);
    return m + log2a(1.0f + exp2a(-fabsf(x - y)));
}
__device__ __forceinline__ float lse3(float x, float y, float z) {
    float m = fmaxf(x, fmaxf(y, z));
    return m + log2a(exp2a(x - m) + exp2a(y - m) + exp2a(z - m));
}

// ---------------- main: one 64-thread block per (n, direction) ----------------
__global__ __launch_bounds__(64) void ctc_half(
    const float* __restrict__ lp, const int* __restrict__ tgt,
    const int* __restrict__ ilen, const int* __restrict__ tlen,
    float* __restrict__ ws, int N)
{
    const int b   = blockIdx.x;
    const int n   = b >> 1;
    const int dir = b & 1;               // 0 = forward, 1 = backward
    const int l   = threadIdx.x;         // lane l owns lattice s=4l..4l+3 (l=63 also 256)

    float* ga = ws + (size_t)n * WROW;   // alpha_{mid-1} (log2 domain out)
    float* gg = ga + 260;                // gamma_mid (log2 domain out)

    const int* tn = tgt + n * S_;
    const int ext1 = tn[2 * l];
    const int ext3 = tn[2 * l + 1];
    const int prev = (l > 0) ? tn[2 * l - 1] : 0;
    const bool skip1 = (l > 0) && (ext1 != prev);                     // skip_ok[4l+1]
    const bool skip3 = (ext3 != ext1);                                // skip_ok[4l+3]
    const bool skb3  = (l < 63) && (tn[2 * l + 2] != ext3);           // skip_ok[4l+5]

    int len = ilen[n];
    len = len < 1 ? 1 : (len > T_ ? T_ : len);
    const int mid = len >> 1;            // fwd frames 0..mid-1; bwd frames mid..len-1

    const size_t rstride = (size_t)N * C_;
    const float* lpn = lp + (size_t)n * C_;
    const float* pB = lpn;
    const float* p1 = lpn + ext1;
    const float* p3 = lpn + ext3;

    float rb[U_], r1[U_], r3[U_];        // register ring (raw log-probs)

    if (dir == 0) {
        // ---------------- forward: alpha_{mid-1} ----------------
        const int last = mid - 1 > 0 ? mid - 1 : 0;
        #pragma unroll
        for (int u = 0; u < U_; ++u) {
            const int r = u + 1;
            const int rc = r < mid ? r : last;
            const size_t o = (size_t)rc * rstride;
            rb[r & 7] = pB[o]; r1[r & 7] = p1[o]; r3[r & 7] = p3[o];
        }
        float m0 = 0.f, m1 = 0.f, m2 = 0.f, m3 = 0.f, m4 = 0.f;
        int E = 0;
        {
            const float i0 = exp2a(pB[0] * LOG2E);
            const float i1 = exp2a(p1[0] * LOG2E);
            if (l == 0) { m0 = i0; m1 = i1; }
        }
        for (int tb = 1; tb < mid; tb += U_) {
            #pragma unroll
            for (int u = 0; u < U_; ++u) {
                const int t = tb + u;
                const int slot = (1 + u) & 7;              // == t&7
                const float pb  = exp2a(rb[slot] * LOG2E);
                const float pe1 = exp2a(r1[slot] * LOG2E);
                const float pe3 = exp2a(r3[slot] * LOG2E);
                const int rr = t + U_;
                const int rc = rr < mid ? rr : last;
                const size_t o = (size_t)rc * rstride;
                const float nrb = pB[o], nr1 = p1[o], nr3 = p3[o];
                if (t < mid) {
                    // cross-lane feed, exact alignment with own-rescale
                    const float s3  = dppf<0x138>(0.f, m3);   // lane l-1's m3 (lane0 -> 0)
                    const int   Eup = dppi<0x138>(E, E);      // lane l-1's E (lane0 -> own)
                    const int   dE  = Eup - E;
                    const int   dc  = dE > DCAP ? DCAP : dE;
                    const float fsc = pow2f(dc - dE);         // own rescale (1 in all live cases)
                    const float aln = s3 * pow2f(dc);         // exact-0 below -127

                    const float m0f = m0 * fsc, m1f = m1 * fsc, m2f = m2 * fsc;
                    const float m3f = m3 * fsc, m4f = m4 * fsc;
                    const float z1 = skip1 ? aln : 0.f;
                    const float z3 = skip3 ? m1f : 0.f;
                    const float n0 = (m0f + aln)       * pb;   // s=4l
                    const float n1 = (m1f + m0f + z1)  * pe1;  // s=4l+1
                    const float n2 = (m2f + m1f)       * pb;   // s=4l+2
                    const float n3 = (m3f + m2f + z3)  * pe3;  // s=4l+3
                    const float n4 = (m4f + m3f)       * pb;   // s=256 (lane63; phantom elsewhere)

                    const float mx = fmaxf(fmaxf(n0, n1), fmaxf(fmaxf(n2, n3), n4));
                    const bool dead = (mx == 0.0f);
                    const int  eb = (__float_as_int(mx) >> 23) & 0xFF;
                    const float sc = __int_as_float((254 - eb) << 23);  // 2^(127-eb)
                    m0 = n0 * sc; m1 = n1 * sc; m2 = n2 * sc;
                    m3 = n3 * sc; m4 = n4 * sc;                         // dead: 0*sc = 0
                    const int Eb = Eup - dc;                   // scale of the n's (== E when fsc==1)
                    const int E1 = dead ? E : (Eb + eb - 127);
                    const int Ein = dppi<0x138>(E1, E1);       // inherit from LEFT
                    E = dead ? Ein : E1;
                }
                rb[slot] = nrb; r1[slot] = nr1; r3[slot] = nr3;
            }
        }
        const float Ef = (float)E;
        ga[4 * l + 0] = fmaxf(log2a(m0) + Ef, NEGC);   // log2(0)=-inf -> NEGC
        ga[4 * l + 1] = fmaxf(log2a(m1) + Ef, NEGC);
        ga[4 * l + 2] = fmaxf(log2a(m2) + Ef, NEGC);
        ga[4 * l + 3] = fmaxf(log2a(m3) + Ef, NEGC);
        if (l == 63) ga[256] = fmaxf(log2a(m4) + Ef, NEGC);
    } else {
        // ---------------- backward: gamma_mid ----------------
        const int fe = len - 1;
        #pragma unroll
        for (int u = 0; u < U_; ++u) {
            int rc = fe - 1 - u; if (rc < 0) rc = 0;
            const size_t o = (size_t)rc * rstride;
            rb[u] = pB[o]; r1[u] = p1[o]; r3[u] = p3[o];
        }
        const int tl = tlen[n];
        const int sA = 2 * tl, sB = 2 * tl - 1;
        float g0, g1, g2, g3, g4;
        // STALE-E FIX: lanes entirely above sA are permanently dead; init
        // E = -2^24 so the top live lane sees dE huge-NEGATIVE (fsc=1,
        // aln=0) instead of huge-positive (own-mass flush).
        int E = (4 * l > sA) ? -BIGE : 0;
        {
            const size_t o = (size_t)fe * rstride;
            const float ebv = exp2a(pB[o] * LOG2E);
            const float e1v = exp2a(p1[o] * LOG2E);
            const float e3v = exp2a(p3[o] * LOG2E);
            const int s0 = 4 * l;
            g0 = (s0     == sA)                 ? ebv : 0.f;
            g1 = (s0 + 1 == sA || s0 + 1 == sB) ? e1v : 0.f;
            g2 = (s0 + 2 == sA)                 ? ebv : 0.f;
            g3 = (s0 + 3 == sA || s0 + 3 == sB) ? e3v : 0.f;
            g4 = (l == 63 && 256 == sA)         ? ebv : 0.f;
        }
        for (int tb = fe - 1; tb >= mid; tb -= U_) {
            #pragma unroll
            for (int u = 0; u < U_; ++u) {
                const int t = tb - u;
                const int slot = ((fe - 1 - tb) + u) & 7;  // == u
                const float pb  = exp2a(rb[slot] * LOG2E);
                const float pe1 = exp2a(r1[slot] * LOG2E);
                const float pe3 = exp2a(r3[slot] * LOG2E);
                int rc = t - U_; if (rc < 0) rc = 0;
                const size_t o = (size_t)rc * rstride;
                const float nrb = pB[o], nr1 = p1[o], nr3 = p3[o];
                if (t >= mid) {
                    const float x0  = dppf<0x130>(g4,  g0);   // lane l+1's g0; l63 -> own g4 (dE=0)
                    const float x1  = dppf<0x130>(0.f, g1);   // lane l+1's g1; l63 -> 0
                    const int   Eup = dppi<0x130>(E, E);      // lane l+1's E (l63 -> own)
                    const int   dE  = Eup - E;
                    const int   dc  = dE > DCAP ? DCAP : dE;
                    const float fsc = pow2f(dc - dE);
                    const float al  = pow2f(dc);
                    const float nx0 = x0 * al, nx1 = x1 * al;

                    const float g0f = g0 * fsc, g1f = g1 * fsc, g2f = g2 * fsc;
                    const float g3f = g3 * fsc, g4f = g4 * fsc;
                    const float z1 = skip3 ? g3f : 0.f;       // skip_ok[4l+3]
                    const float z3 = skb3  ? nx1 : 0.f;       // skip_ok[4l+5]
                    const float n0 = (g0f + g1f)        * pb;  // s=4l
                    const float n1 = (g1f + g2f + z1)   * pe1; // s=4l+1
                    const float n2 = (g2f + g3f)        * pb;  // s=4l+2
                    const float n3 = (g3f + nx0 + z3)   * pe3; // s=4l+3
                    const float n4 = g4f                * pb;  // s=256: stay only

                    const float mx = fmaxf(fmaxf(n0, n1), fmaxf(fmaxf(n2, n3), n4));
                    const bool dead = (mx == 0.0f);
                    const int  eb = (__float_as_int(mx) >> 23) & 0xFF;
                    const float sc = __int_as_float((254 - eb) << 23);
                    g0 = n0 * sc; g1 = n1 * sc; g2 = n2 * sc;
                    g3 = n3 * sc; g4 = n4 * sc;
                    const int Eb = Eup - dc;
                    const int E1 = dead ? E : (Eb + eb - 127);
                    const int Ein = dppi<0x130>(E1, E1);      // inherit from RIGHT
                    E = dead ? Ein : E1;
                }
                rb[slot] = nrb; r1[slot] = nr1; r3[slot] = nr3;
            }
        }
        const float Ef = (float)E;
        gg[4 * l + 0] = fmaxf(log2a(g0) + Ef, NEGC);
        gg[4 * l + 1] = fmaxf(log2a(g1) + Ef, NEGC);
        gg[4 * l + 2] = fmaxf(log2a(g2) + Ef, NEGC);
        gg[4 * l + 3] = fmaxf(log2a(g3) + Ef, NEGC);
        if (l == 63) gg[256] = fmaxf(log2a(g4) + Ef, NEGC);
    }
}

// ---------------- combine: P = sum_s abar[s] * gamma_mid[s] (R9, proven) ----------------
__global__ __launch_bounds__(64) void ctc_comb(
    const float* __restrict__ ws, const int* __restrict__ tgt,
    const int* __restrict__ ilen, const int* __restrict__ tlen,
    float* __restrict__ out, int N)
{
    const int n = blockIdx.x;
    const int l = threadIdx.x;
    const float* ga = ws + (size_t)n * WROW;
    const float* gg = ga + 260;

    int len = ilen[n];
    len = len < 1 ? 1 : (len > T_ ? T_ : len);
    const int tl = tlen[n];

    if (len == 1) {
        if (l == 0) {
            const float v1 = ga[2 * tl];
            const float v2 = (2 * tl >= 1) ? ga[2 * tl - 1] : NEGC;
            float loss = -lse2(v1, v2) * LN2;
            if (!(loss < 1e10f) || !isfinite(loss)) loss = 0.0f;
            out[n] = loss;
        }
        return;
    }

    const int* tn = tgt + n * S_;
    const int ext1 = tn[2 * l];
    const int ext3 = tn[2 * l + 1];
    const int prev = (l > 0) ? tn[2 * l - 1] : 0;
    const bool skip1 = (l > 0) && (ext1 != prev);
    const bool skip3 = (ext3 != ext1);

    const int s0 = 4 * l;
    const float Am1 = (l > 0) ? ga[s0 - 1] : NEGC;
    const float A0 = ga[s0], A1 = ga[s0 + 1], A2 = ga[s0 + 2], A3 = ga[s0 + 3];
    const float v0 = lse2(A0, Am1)                    + gg[s0];
    const float v1 = lse3(A1, A0, skip1 ? Am1 : NEGC) + gg[s0 + 1];
    const float v2 = lse2(A2, A1)                     + gg[s0 + 2];
    const float v3 = lse3(A3, A2, skip3 ? A1 : NEGC)  + gg[s0 + 3];
    const float v4 = (l == 63) ? (lse2(ga[256], A3) + gg[256]) : NEGC;

    float m = fmaxf(fmaxf(v0, v1), fmaxf(fmaxf(v2, v3), v4));
    float ssum = exp2a(v0 - m) + exp2a(v1 - m) + exp2a(v2 - m)
               + exp2a(v3 - m) + exp2a(v4 - m);
    float M = m;
    #pragma unroll
    for (int d = 1; d < 64; d <<= 1) M = fmaxf(M, __shfl_xor(M, d));
    float r = ssum * exp2a(m - M);
    #pragma unroll
    for (int d = 1; d < 64; d <<= 1) r += __shfl_xor(r, d);
    if (l == 0) {
        float loss = -LN2 * (M + log2a(r));
        if (!(loss < 1e10f) || !isfinite(loss)) loss = 0.0f;
        out[n] = loss;
    }
}

// ---------------- fallback: R8 fused kernel (proven) ----------------
__global__ __launch_bounds__(128) void ctc_fused(
    const float* __restrict__ lp, const int* __restrict__ tgt,
    const int* __restrict__ ilen, const int* __restrict__ tlen,
    float* __restrict__ out, int N)
{
    const int n    = blockIdx.x;
    const int wave = threadIdx.x >> 6;
    const int l    = threadIdx.x & 63;

    __shared__ float ga[2 * S_ + 1];
    __shared__ float gg[2 * S_ + 1];

    const int* tn = tgt + n * S_;
    const int ext1 = tn[2 * l];
    const int ext3 = tn[2 * l + 1];
    const int prev = (l > 0) ? tn[2 * l - 1] : 0;
    const bool skip1 = (l > 0) && (ext1 != prev);
    const bool skip3 = (ext3 != ext1);
    const bool skb1 = (tn[2 * l + 1] != tn[2 * l]);
    const bool skb3 = (l < 63) && (tn[2 * l + 2] != tn[2 * l + 1]);

    int len = ilen[n];
    len = len < 1 ? 1 : (len > T_ ? T_ : len);
    const int mid = len >> 1;

    const size_t rstride = (size_t)N * C_;
    const float* lpn = lp + (size_t)n * C_;
    const float* pB = lpn;
    const float* p1 = lpn + ext1;
    const float* p3 = lpn + ext3;

    float rb[U_], r1[U_], r3[U_];

    if (wave == 0) {
        const int last = mid - 1 > 0 ? mid - 1 : 0;
        #pragma unroll
        for (int u = 0; u < U_; ++u) {
            const int r = u + 1;
            const int rc = r < mid ? r : last;
            const size_t o = (size_t)rc * rstride;
            rb[r & 7] = pB[o]; r1[r & 7] = p1[o]; r3[r & 7] = p3[o];
        }
        float a0 = NEGC, a1 = NEGC, a2 = NEGC, a3 = NEGC, a4 = NEGC;
        {
            const float i0 = pB[0] * LOG2E;
            const float i1 = p1[0] * LOG2E;
            if (l == 0) { a0 = i0; a1 = i1; }
        }
        for (int tb = 1; tb < mid; tb += U_) {
            #pragma unroll
            for (int u = 0; u < U_; ++u) {
                const int t = tb + u;
                const int slot = (1 + u) & 7;
                const float eb = rb[slot] * LOG2E;
                const float e1 = r1[slot] * LOG2E;
                const float e3 = r3[slot] * LOG2E;
                const int rr = t + U_;
                const int rc = rr < mid ? rr : last;
                const size_t o = (size_t)rc * rstride;
                const float nrb = pB[o], nr1 = p1[o], nr3 = p3[o];
                if (t < mid) {
                    const float sm1 = dppf<0x138>(NEGC, a3);
                    const float z1 = skip1 ? sm1 : NEGC;
                    const float z3 = skip3 ? a1  : NEGC;
                    const float n0 = lse2(a0, sm1)    + eb;
                    const float n1 = lse3(a1, a0, z1) + e1;
                    const float n2 = lse2(a2, a1)     + eb;
                    const float n3 = lse3(a3, a2, z3) + e3;
                    const float n4 = lse2(a4, a3)     + eb;
                    a0 = n0; a1 = n1; a2 = n2; a3 = n3; a4 = n4;
                }
                rb[slot] = nrb; r1[slot] = nr1; r3[slot] = nr3;
            }
        }
        ga[4 * l + 0] = a0; ga[4 * l + 1] = a1;
        ga[4 * l + 2] = a2; ga[4 * l + 3] = a3;
        if (l == 63) ga[256] = a4;
    } else {
        const int fe = len - 1;
        #pragma unroll
        for (int u = 0; u < U_; ++u) {
            int rc = fe - 1 - u; if (rc < 0) rc = 0;
            const size_t o = (size_t)rc * rstride;
            rb[u] = pB[o]; r1[u] = p1[o]; r3[u] = p3[o];
        }
        const int tl = tlen[n];
        const int sA = 2 * tl, sB = 2 * tl - 1;
        float g0, g1, g2, g3, g4;
        {
            const size_t o = (size_t)fe * rstride;
            const float ebi = pB[o] * LOG2E;
            const float e1i = p1[o] * LOG2E;
            const float e3i = p3[o] * LOG2E;
            const int s0 = 4 * l;
            g0 = (s0     == sA)                 ? ebi : NEGC;
            g1 = (s0 + 1 == sA || s0 + 1 == sB) ? e1i : NEGC;
            g2 = (s0 + 2 == sA)                 ? ebi : NEGC;
            g3 = (s0 + 3 == sA || s0 + 3 == sB) ? e3i : NEGC;
            g4 = (l == 63 && 256 == sA)         ? ebi : NEGC;
        }
        for (int tb = fe - 1; tb >= mid; tb -= U_) {
            #pragma unroll
            for (int u = 0; u < U_; ++u) {
                const int t = tb - u;
                const int slot = ((fe - 1 - tb) + u) & 7;
                const float eb = rb[slot] * LOG2E;
                const float e1 = r1[slot] * LOG2E;
                const float e3 = r3[slot] * LOG2E;
                int rc = t - U_; if (rc < 0) rc = 0;
                const size_t o = (size_t)rc * rstride;
                const float nrb = pB[o], nr1 = p1[o], nr3 = p3[o];
                if (t >= mid) {
                    const float nx0 = dppf<0x130>(g4,   g0);
                    const float nx1 = dppf<0x130>(NEGC, g1);
                    const float z1 = skb1 ? g3  : NEGC;
                    const float z3 = skb3 ? nx1 : NEGC;
                    const float n0 = lse2(g0, g1)      + eb;
                    const float n1 = lse3(g1, g2, z1)  + e1;
                    const float n2 = lse2(g2, g3)      + eb;
                    const float n3 = lse3(g3, nx0, z3) + e3;
                    const float n4 = g4 + eb;
                    g0 = n0; g1 = n1; g2 = n2; g3 = n3; g4 = n4;
                }
                rb[slot] = nrb; r1[slot] = nr1; r3[slot] = nr3;
            }
        }
        gg[4 * l + 0] = g0; gg[4 * l + 1] = g1;
        gg[4 * l + 2] = g2; gg[4 * l + 3] = g3;
        if (l == 63) gg[256] = g4;
    }

    __syncthreads();

    if (wave == 0) {
        const int tl = tlen[n];
        if (len == 1) {
            if (l == 0) {
                const float v1 = ga[2 * tl];
                const float v2 = (2 * tl >= 1) ? ga[2 * tl - 1] : NEGC;
                float loss = -lse2(v1, v2) * LN2;
                if (!(loss < 1e10f) || !isfinite(loss)) loss = 0.0f;
                out[n] = loss;
            }
            return;
        }
        const int s0 = 4 * l;
        const float Am1 = (l > 0) ? ga[s0 - 1] : NEGC;
        const float A0 = ga[s0], A1 = ga[s0 + 1], A2 = ga[s0 + 2], A3 = ga[s0 + 3];
        const float v0 = lse2(A0, Am1)                    + gg[s0];
        const float v1 = lse3(A1, A0, skip1 ? Am1 : NEGC) + gg[s0 + 1];
        const float v2 = lse2(A2, A1)                     + gg[s0 + 2];
        const float v3 = lse3(A3, A2, skip3 ? A1 : NEGC)  + gg[s0 + 3];
        const float v4 = (l == 63) ? (lse2(ga[256], A3) + gg[256]) : NEGC;

        float m = fmaxf(fmaxf(v0, v1), fmaxf(fmaxf(v2, v3), v4));
        float ssum = exp2a(v0 - m) + exp2a(v1 - m) + exp2a(v2 - m)
                   + exp2a(v3 - m) + exp2a(v4 - m);
        float M = m;
        #pragma unroll
        for (int d = 1; d < 64; d <<= 1) M = fmaxf(M, __shfl_xor(M, d));
        float r = ssum * exp2a(m - M);
        #pragma unroll
        for (int d = 1; d < 64; d <<= 1) r += __shfl_xor(r, d);
        if (l == 0) {
            float loss = -LN2 * (M + log2a(r));
            if (!(loss < 1e10f) || !isfinite(loss)) loss = 0.0f;
            out[n] = loss;
        }
    }
}

extern "C" void kernel_launch(void* const* d_in, const int* in_sizes, int n_in,
                              void* d_out, int out_size, void* d_ws, size_t ws_size,
                              hipStream_t stream) {
    const float* lp  = (const float*)d_in[0];
    const int*   tg  = (const int*)  d_in[1];
    const int*   il  = (const int*)  d_in[2];
    const int*   tl  = (const int*)  d_in[3];
    float*       out = (float*)d_out;
    const int N = in_sizes[2];  // 512
    const size_t need = (size_t)N * WROW * sizeof(float);  // ~1.06 MB
    if (ws_size >= need) {
        ctc_half<<<2 * N, 64, 0, stream>>>(lp, tg, il, tl, (float*)d_ws, N);
        ctc_comb<<<N, 64, 0, stream>>>((const float*)d_ws, tg, il, tl, out, N);
    } else {
        ctc_fused<<<N, 128, 0, stream>>>(lp, tg, il, tl, out, N);  // proven R8 path
    }
}